// Round 2
// baseline (81.036 us; speedup 1.0000x reference)
//
#include <hip/hip_runtime.h>
#include <cstdint>

// Ball query: B=8, N=4096, radius=0.2, nsample=32. Queries == sources.
// Output int32 (B,N,32): first 32 in-radius indices ascending, padded with
// the first match.
//
// NUMERICS (LOCKED, R8-verified absmax=0): expansion form f32,
//   sq  = (x*x + y*y) + z*z              -- plain, no FMA
//   dot = fma(qz,sz, fma(qy,sy, qx*sx))  -- FMA, K ascending
//   d2  = (sqq + sqs) - (dot + dot)
//   match = d2 < 0.04f
// All in inline asm -- immune to -ffast-math/contract. DO NOT CHANGE.
// (R13: sq is now computed ONCE per point in pack_kernel with the SAME
//  sq_plain asm -- bit-identical to recomputing per use.)
//
// R13 perf theory: R12 (~37.5us kernel) was stall-bound, not VALU-bound
// (~10us floor): (a) 3x dword stride-12 scan loads re-walk the same cache
// lines and re-run sq_plain every round; (b) chunk c+1 loads sit behind the
// break branch that depends on chunk c ballots -> serial L2 latency per
// chunk. R13: pack (x,y,z,sq) as float4 in d_ws (one dwordx4/lane/round,
// no per-round sq) + manual ping-pong chunk prefetch across the break
// (speculative clamped load of c+1 before processing c). Fallback to the
// R12 direct-read kernel if ws_size < 512KB.

#define BQ_N    4096
#define BQ_B    8
#define BQ_NS   32
#define BQ_R2   0.04f
#define BQ_NC   16    // chunks of 256 points (4 rounds of 64)

__device__ __forceinline__ float sq_plain(float x, float y, float z) {
    float r, t;
    asm("v_mul_f32 %0, %2, %2\n\t"
        "v_mul_f32 %1, %3, %3\n\t"
        "v_add_f32 %0, %0, %1\n\t"
        "v_mul_f32 %1, %4, %4\n\t"
        "v_add_f32 %0, %0, %1"
        : "=&v"(r), "=&v"(t)
        : "v"(x), "v"(y), "v"(z));
    return r;
}

__device__ __forceinline__ float d2_mixed(float qx, float qy, float qz, float sqq,
                                          float sx, float sy, float sz, float sqs) {
    float r, t;
    asm("v_mul_f32 %0, %2, %5\n\t"     // qx*sx
        "v_fma_f32 %0, %3, %6, %0\n\t" // + qy*sy (fused)
        "v_fma_f32 %0, %4, %7, %0\n\t" // + qz*sz (fused) = dot
        "v_add_f32 %0, %0, %0\n\t"     // 2*dot (exact)
        "v_add_f32 %1, %8, %9\n\t"     // sqq + sqs
        "v_sub_f32 %0, %1, %0"         // d2
        : "=&v"(r), "=&v"(t)
        : "v"(qx), "v"(qy), "v"(qz), "v"(sx), "v"(sy), "v"(sz),
          "v"(sqq), "v"(sqs));
    return r;
}

// ---------------------------------------------------------------- packed path

__global__ __launch_bounds__(256)
void pack_kernel(const float* __restrict__ xyz, float4* __restrict__ pk)
{
    const int i = blockIdx.x * 256 + threadIdx.x;    // 0 .. B*N-1
    const float x = xyz[3 * i + 0];
    const float y = xyz[3 * i + 1];
    const float z = xyz[3 * i + 2];
    pk[i] = make_float4(x, y, z, sq_plain(x, y, z));
}

__device__ __forceinline__ void load_chunk(const float4* __restrict__ pp,
                                           int lane, int c, float4 S[4])
{
    #pragma unroll
    for (int u = 0; u < 4; ++u)
        S[u] = pp[(((c << 2) + u) << 6) + lane];     // one dwordx4 per round
}

// Process one staged chunk for a dual-query cascade. Captures per-round
// ballot word AND exclusive prefix (wpre) at lane==k -- emit needs no scan.
__device__ __forceinline__ void proc2(const float4 S[4], int lane, int c,
                                      const float4& q0, const float4& q1,
                                      uint64_t& w0, uint64_t& w1,
                                      int& p0, int& p1, int& f0, int& f1)
{
    #pragma unroll
    for (int u = 0; u < 4; ++u) {
        const int k = (c << 2) + u;
        const float d20 = d2_mixed(q0.x, q0.y, q0.z, q0.w,
                                   S[u].x, S[u].y, S[u].z, S[u].w);
        const float d21 = d2_mixed(q1.x, q1.y, q1.z, q1.w,
                                   S[u].x, S[u].y, S[u].z, S[u].w);
        const uint64_t b0 = __ballot(d20 < BQ_R2);
        const uint64_t b1 = __ballot(d21 < BQ_R2);
        if (lane == k) { w0 = b0; w1 = b1; p0 = f0; p1 = f1; }
        f0 += (int)__popcll(b0);
        f1 += (int)__popcll(b1);
    }
}

// Single-query chunk (tail after the pair's OR-break). No prefetch: rare path.
__device__ __forceinline__ void scan1p(const float4* __restrict__ pp, int lane,
                                       const float4& q, int c,
                                       uint64_t& word, int& wpre, int& found)
{
    float4 S[4];
    load_chunk(pp, lane, c, S);
    #pragma unroll
    for (int u = 0; u < 4; ++u) {
        const int k = (c << 2) + u;
        const float d2 = d2_mixed(q.x, q.y, q.z, q.w,
                                  S[u].x, S[u].y, S[u].z, S[u].w);
        const uint64_t bal = __ballot(d2 < BQ_R2);
        if (lane == k) { word = bal; wpre = found; }
        found += (int)__popcll(bal);
    }
}

// Dual-query cascade over all 16 chunks with ping-pong prefetch: the loads
// for chunk c+1 (clamped; speculative reload of 15 is harmless) issue BEFORE
// chunk c's ballots/break, so L2 latency hides under compute.
__device__ __forceinline__ void scan2p(const float4* __restrict__ pp, int lane,
                                       const float4& q0, const float4& q1,
                                       uint64_t& w0, uint64_t& w1,
                                       int& p0, int& p1, int& f0, int& f1)
{
    float4 A[4], B[4];
    load_chunk(pp, lane, 0, A);
    int c = 0;
    for (;;) {
        int cn = (c + 1 < BQ_NC) ? c + 1 : c;
        load_chunk(pp, lane, cn, B);
        proc2(A, lane, c, q0, q1, w0, w1, p0, p1, f0, f1);
        ++c;
        if (c >= BQ_NC || f0 >= BQ_NS || f1 >= BQ_NS) break;   // uniform

        cn = (c + 1 < BQ_NC) ? c + 1 : c;
        load_chunk(pp, lane, cn, A);
        proc2(B, lane, c, q0, q1, w0, w1, p0, p1, f0, f1);
        ++c;
        if (c >= BQ_NC || f0 >= BQ_NS || f1 >= BQ_NS) break;   // uniform
    }
    for (int ca = c; ca < BQ_NC && f0 < BQ_NS; ++ca) scan1p(pp, lane, q0, ca, w0, p0, f0);
    for (int cb = c; cb < BQ_NC && f1 < BQ_NS; ++cb) scan1p(pp, lane, q1, cb, w1, p1, f1);
}

// Prefix-free emit: lane k holds round-k word and wpre (= matches before
// round k, captured during scan). Pure stores; padding only when total<32.
__device__ __forceinline__ void emit_query(int* __restrict__ orow, int lane,
                                           uint64_t word, int wpre, int total)
{
    uint64_t w = word;
    int pos = wpre;                      // >=32 for overshoot rounds -> skipped
    while (w != 0ull && pos < BQ_NS) {
        const int bit = __builtin_ctzll(w);
        orow[pos] = (lane << 6) + bit;   // lane == round k; ascending order
        w &= (w - 1);
        ++pos;
    }
    if (total < BQ_NS) {                 // rare (queries with <32 neighbors)
        int first;
        const uint64_t nz = __ballot(word != 0ull);
        if (nz == 0ull) {
            first = BQ_N;   // defensive; self-match (|d2|<=2e-7) makes this unreachable
        } else {
            const int fl = __builtin_ctzll(nz);
            const uint64_t fw = __shfl(word, fl);
            first = (fl << 6) + __builtin_ctzll(fw);
        }
        if (lane >= total && lane < BQ_NS) orow[lane] = first;
    }
}

__global__ __launch_bounds__(128, 4)
void ball_query_packed(const float4* __restrict__ pk, int* __restrict__ out)
{
    const int b     = blockIdx.x >> 9;          // 512 blocks per batch
    const int qbase = (blockIdx.x & 511) << 3;  // 8 queries per block
    const int lane  = threadIdx.x & 63;
    const int wid   = threadIdx.x >> 6;         // 2 independent waves/block
    const float4* __restrict__ pp = pk + (size_t)b * BQ_N;
    int* __restrict__ outb = out + (size_t)(b * BQ_N) * BQ_NS;

    float4 Q[4];
    #pragma unroll
    for (int j = 0; j < 4; ++j)
        Q[j] = pp[qbase + (wid << 2) + j];      // (x,y,z,sq) precomputed

    uint64_t W[4] = {0, 0, 0, 0};
    int      P[4] = {0, 0, 0, 0};
    int      F[4] = {0, 0, 0, 0};

    scan2p(pp, lane, Q[0], Q[1], W[0], W[1], P[0], P[1], F[0], F[1]);
    scan2p(pp, lane, Q[2], Q[3], W[2], W[3], P[2], P[3], F[2], F[3]);

    #pragma unroll
    for (int j = 0; j < 4; ++j) {
        const int m = qbase + (wid << 2) + j;
        emit_query(outb + (size_t)m * BQ_NS, lane, W[j], P[j], F[j]);
    }
}

// ------------------------------------------------- fallback (R12, direct read)

__device__ __forceinline__ void scan1g(const float* __restrict__ src, int lane,
                                       const float4& q, int c,
                                       uint64_t& word, int& wpre, int& found)
{
    float X[4], Y[4], Z[4];
    #pragma unroll
    for (int u = 0; u < 4; ++u) {
        const int k = (c << 2) + u;
        const float* ptr = src + (size_t)(((k << 6) + lane) * 3);
        X[u] = ptr[0]; Y[u] = ptr[1]; Z[u] = ptr[2];
    }
    #pragma unroll
    for (int u = 0; u < 4; ++u) {
        const int k = (c << 2) + u;
        const float sqs = sq_plain(X[u], Y[u], Z[u]);
        const float d2  = d2_mixed(q.x, q.y, q.z, q.w, X[u], Y[u], Z[u], sqs);
        const uint64_t bal = __ballot(d2 < BQ_R2);
        if (lane == k) { word = bal; wpre = found; }
        found += (int)__popcll(bal);
    }
}

__device__ __forceinline__ void scan2g(const float* __restrict__ src, int lane,
                                       const float4& q0, const float4& q1,
                                       uint64_t& w0, uint64_t& w1,
                                       int& p0, int& p1, int& f0, int& f1)
{
    int c = 0;
    while (c < BQ_NC) {
        float X[4], Y[4], Z[4];
        #pragma unroll
        for (int u = 0; u < 4; ++u) {
            const int k = (c << 2) + u;
            const float* ptr = src + (size_t)(((k << 6) + lane) * 3);
            X[u] = ptr[0]; Y[u] = ptr[1]; Z[u] = ptr[2];
        }
        #pragma unroll
        for (int u = 0; u < 4; ++u) {
            const int k = (c << 2) + u;
            const float sqs = sq_plain(X[u], Y[u], Z[u]);
            const float d20 = d2_mixed(q0.x, q0.y, q0.z, q0.w, X[u], Y[u], Z[u], sqs);
            const float d21 = d2_mixed(q1.x, q1.y, q1.z, q1.w, X[u], Y[u], Z[u], sqs);
            const uint64_t b0 = __ballot(d20 < BQ_R2);
            const uint64_t b1 = __ballot(d21 < BQ_R2);
            if (lane == k) { w0 = b0; w1 = b1; p0 = f0; p1 = f1; }
            f0 += (int)__popcll(b0);
            f1 += (int)__popcll(b1);
        }
        ++c;
        if (f0 >= BQ_NS || f1 >= BQ_NS) break;
    }
    for (int ca = c; ca < BQ_NC && f0 < BQ_NS; ++ca) scan1g(src, lane, q0, ca, w0, p0, f0);
    for (int cb = c; cb < BQ_NC && f1 < BQ_NS; ++cb) scan1g(src, lane, q1, cb, w1, p1, f1);
}

__global__ __launch_bounds__(128, 4)
void ball_query_kernel(const float* __restrict__ xyz, int* __restrict__ out)
{
    const int b     = blockIdx.x >> 9;
    const int qbase = (blockIdx.x & 511) << 3;
    const int lane  = threadIdx.x & 63;
    const int wid   = threadIdx.x >> 6;
    const float* __restrict__ src = xyz + (size_t)b * BQ_N * 3;
    int* __restrict__ outb = out + (size_t)(b * BQ_N) * BQ_NS;

    float4 Q[4];
    #pragma unroll
    for (int j = 0; j < 4; ++j) {
        const int m = qbase + (wid << 2) + j;
        const float x = src[3 * m + 0];
        const float y = src[3 * m + 1];
        const float z = src[3 * m + 2];
        Q[j] = make_float4(x, y, z, sq_plain(x, y, z));
    }

    uint64_t W[4] = {0, 0, 0, 0};
    int      P[4] = {0, 0, 0, 0};
    int      F[4] = {0, 0, 0, 0};

    scan2g(src, lane, Q[0], Q[1], W[0], W[1], P[0], P[1], F[0], F[1]);
    scan2g(src, lane, Q[2], Q[3], W[2], W[3], P[2], P[3], F[2], F[3]);

    #pragma unroll
    for (int j = 0; j < 4; ++j) {
        const int m = qbase + (wid << 2) + j;
        emit_query(outb + (size_t)m * BQ_NS, lane, W[j], P[j], F[j]);
    }
}

// ----------------------------------------------------------------- launch

extern "C" void kernel_launch(void* const* d_in, const int* in_sizes, int n_in,
                              void* d_out, int out_size, void* d_ws, size_t ws_size,
                              hipStream_t stream)
{
    const float* xyz = (const float*)d_in[0];   // (8, 4096, 3) f32; d_in[1] unused
    int* out = (int*)d_out;                     // (8, 4096, 32) int32
    const size_t pk_bytes = (size_t)BQ_B * BQ_N * sizeof(float4);   // 512 KiB
    if (d_ws != nullptr && ws_size >= pk_bytes) {
        float4* pk = (float4*)d_ws;
        hipLaunchKernelGGL(pack_kernel, dim3((BQ_B * BQ_N) / 256), dim3(256),
                           0, stream, xyz, pk);
        hipLaunchKernelGGL(ball_query_packed, dim3(4096), dim3(128), 0, stream,
                           pk, out);
    } else {
        hipLaunchKernelGGL(ball_query_kernel, dim3(4096), dim3(128), 0, stream,
                           xyz, out);
    }
}

// Round 3
// 79.669 us; speedup vs baseline: 1.0172x; 1.0172x over previous
//
#include <hip/hip_runtime.h>
#include <cstdint>

// Ball query: B=8, N=4096, radius=0.2, nsample=32. Queries == sources.
// Output int32 (B,N,32): first 32 in-radius indices ascending, padded with
// the first match.
//
// NUMERICS (LOCKED, R8-verified absmax=0): expansion form f32,
//   sq  = (x*x + y*y) + z*z              -- plain, no FMA
//   dot = fma(qz,sz, fma(qy,sy, qx*sx))  -- FMA, K ascending
//   d2  = (sqq + sqs) - (dot + dot)
//   match = d2 < 0.04f
// All in inline asm -- immune to -ffast-math/contract. DO NOT CHANGE.
// sq for scan points recomputed per chunk-round with the same asm
// (bit-identical; shared across the wave's 8 queries).
//
// R14 perf theory: R12->R13 (packed loads + ping-pong prefetch) was flat ->
// kernel is BYTE-bound (L1/L2), not latency-bound. 78% of queries sit
// within radius of a cube face -> deep scans; dual cascade = max(c0,c1)
// ~10 chunks/pair ~ 600MB L1/L2 traffic ~ the whole 38us. R14: ONE wave
// owns EIGHT queries, single shared scan with per-chunk wave-uniform skip
// (readfirstlane -> s_cbranch, skipped queries cost no issue slots).
// Chunk loads/wave = max over 8 ~ 14.5 -> bytes/query down 2.6x (~180MB).
// VALU ~ sum of per-query chunk needs (unchanged ~9us aggregate).
// 2048 blocks x 128 thr (2 independent waves/block), no LDS, no barriers,
// double-buffered chunk prefetch, prefix-free emit.

#define BQ_N    4096
#define BQ_B    8
#define BQ_NS   32
#define BQ_R2   0.04f
#define BQ_NC   16    // chunks of 256 points (4 rounds of 64)

__device__ __forceinline__ float sq_plain(float x, float y, float z) {
    float r, t;
    asm("v_mul_f32 %0, %2, %2\n\t"
        "v_mul_f32 %1, %3, %3\n\t"
        "v_add_f32 %0, %0, %1\n\t"
        "v_mul_f32 %1, %4, %4\n\t"
        "v_add_f32 %0, %0, %1"
        : "=&v"(r), "=&v"(t)
        : "v"(x), "v"(y), "v"(z));
    return r;
}

__device__ __forceinline__ float d2_mixed(float qx, float qy, float qz, float sqq,
                                          float sx, float sy, float sz, float sqs) {
    float r, t;
    asm("v_mul_f32 %0, %2, %5\n\t"     // qx*sx
        "v_fma_f32 %0, %3, %6, %0\n\t" // + qy*sy (fused)
        "v_fma_f32 %0, %4, %7, %0\n\t" // + qz*sz (fused) = dot
        "v_add_f32 %0, %0, %0\n\t"     // 2*dot (exact)
        "v_add_f32 %1, %8, %9\n\t"     // sqq + sqs
        "v_sub_f32 %0, %1, %0"         // d2
        : "=&v"(r), "=&v"(t)
        : "v"(qx), "v"(qy), "v"(qz), "v"(sx), "v"(sy), "v"(sz),
          "v"(sqq), "v"(sqs));
    return r;
}

__device__ __forceinline__ int rfl(int v) {
    return __builtin_amdgcn_readfirstlane(v);   // force scalar branch conds
}

// Load chunk c (4 rounds x 64 pts): three stride-12 dwords per round.
// 768B payload/round; line repeats are L1 hits (R13 showed packed float4
// with 1024B/round + pack kernel is NOT faster -> direct is kept).
__device__ __forceinline__ void loadc(const float* __restrict__ src, int lane,
                                      int c, float X[4], float Y[4], float Z[4])
{
    #pragma unroll
    for (int u = 0; u < 4; ++u) {
        const int k = (c << 2) + u;
        const float* p = src + (size_t)(((k << 6) + lane) * 3);
        X[u] = p[0]; Y[u] = p[1]; Z[u] = p[2];
    }
}

// Process one staged chunk for all still-active queries. The skip branch is
// wave-uniform (rfl -> s_cmp/s_cbranch): finished queries cost nothing.
// Captures per-round ballot word AND exclusive prefix (wpre) at lane==k.
__device__ __forceinline__ void procc(const float X[4], const float Y[4],
                                      const float Z[4], int lane, int c,
                                      const float4 Q[8], uint64_t W[8],
                                      int P[8], int F[8])
{
    float SQ[4];
    #pragma unroll
    for (int u = 0; u < 4; ++u) SQ[u] = sq_plain(X[u], Y[u], Z[u]);

    #pragma unroll
    for (int j = 0; j < 8; ++j) {
        if (rfl(F[j]) < BQ_NS) {
            #pragma unroll
            for (int u = 0; u < 4; ++u) {
                const int k = (c << 2) + u;
                const float d2 = d2_mixed(Q[j].x, Q[j].y, Q[j].z, Q[j].w,
                                          X[u], Y[u], Z[u], SQ[u]);
                const uint64_t bal = __ballot(d2 < BQ_R2);
                if (lane == k) { W[j] = bal; P[j] = F[j]; }
                F[j] += (int)__popcll(bal);
            }
        }
    }
}

__device__ __forceinline__ bool alldone(const int F[8]) {
    int m = F[0];
    #pragma unroll
    for (int j = 1; j < 8; ++j) m = min(m, F[j]);
    return rfl(m) >= BQ_NS;
}

// Prefix-free emit: lane k holds round-k word and wpre (= matches before
// round k, captured during scan). Pure stores; padding only when total<32.
__device__ __forceinline__ void emit_query(int* __restrict__ orow, int lane,
                                           uint64_t word, int wpre, int total)
{
    uint64_t w = word;
    int pos = wpre;                      // >=32 for overshoot rounds -> skipped
    while (w != 0ull && pos < BQ_NS) {
        const int bit = __builtin_ctzll(w);
        orow[pos] = (lane << 6) + bit;   // lane == round k; ascending order
        w &= (w - 1);
        ++pos;
    }
    if (total < BQ_NS) {                 // rare (queries with <32 neighbors)
        int first;
        const uint64_t nz = __ballot(word != 0ull);
        if (nz == 0ull) {
            first = BQ_N;   // defensive; self-match (|d2|<=2e-7) makes this unreachable
        } else {
            const int fl = __builtin_ctzll(nz);
            const uint64_t fw = __shfl(word, fl);
            first = (fl << 6) + __builtin_ctzll(fw);
        }
        if (lane >= total && lane < BQ_NS) orow[lane] = first;
    }
}

__global__ __launch_bounds__(128, 4)
void ball_query_kernel(const float* __restrict__ xyz, int* __restrict__ out)
{
    const int b    = blockIdx.x >> 8;            // 256 blocks per batch
    const int wq   = ((blockIdx.x & 255) << 4) + ((threadIdx.x >> 6) << 3);
    const int lane = threadIdx.x & 63;           // wave owns queries wq..wq+7
    const float* __restrict__ src = xyz + (size_t)b * BQ_N * 3;
    int* __restrict__ outb = out + (size_t)(b * BQ_N) * BQ_NS;

    // Wave's 8 query points (wave-uniform addresses -> scalar/L2).
    float4 Q[8];
    #pragma unroll
    for (int j = 0; j < 8; ++j) {
        const int m = wq + j;
        const float x = src[3 * m + 0];
        const float y = src[3 * m + 1];
        const float z = src[3 * m + 2];
        Q[j] = make_float4(x, y, z, sq_plain(x, y, z));
    }

    uint64_t W[8] = {0, 0, 0, 0, 0, 0, 0, 0};
    int      P[8] = {0, 0, 0, 0, 0, 0, 0, 0};
    int      F[8] = {0, 0, 0, 0, 0, 0, 0, 0};

    // Single shared scan, double-buffered prefetch across the break check
    // (speculative clamped load of c+1 is harmless).
    float XA[4], YA[4], ZA[4], XB[4], YB[4], ZB[4];
    loadc(src, lane, 0, XA, YA, ZA);

    int c = 0;
    for (;;) {
        int cn = (c + 1 < BQ_NC) ? c + 1 : c;
        loadc(src, lane, cn, XB, YB, ZB);
        procc(XA, YA, ZA, lane, c, Q, W, P, F);
        ++c;
        if (c >= BQ_NC || alldone(F)) break;

        cn = (c + 1 < BQ_NC) ? c + 1 : c;
        loadc(src, lane, cn, XA, YA, ZA);
        procc(XB, YB, ZB, lane, c, Q, W, P, F);
        ++c;
        if (c >= BQ_NC || alldone(F)) break;
    }

    #pragma unroll
    for (int j = 0; j < 8; ++j)
        emit_query(outb + (size_t)(wq + j) * BQ_NS, lane, W[j], P[j], F[j]);
}

extern "C" void kernel_launch(void* const* d_in, const int* in_sizes, int n_in,
                              void* d_out, int out_size, void* d_ws, size_t ws_size,
                              hipStream_t stream)
{
    const float* xyz = (const float*)d_in[0];   // (8, 4096, 3) f32; d_in[1] unused
    int* out = (int*)d_out;                     // (8, 4096, 32) int32
    hipLaunchKernelGGL(ball_query_kernel, dim3(2048), dim3(128), 0, stream,
                       xyz, out);
}